// Round 9
// baseline (20.969 us; speedup 1.0000x reference)
//
#include <hip/hip_runtime.h>

#define HH 512
#define WW 512
#define TC 256    // tile cols
#define TR 16     // tile rows
#define NXCD 8

typedef float f32x4 __attribute__((ext_vector_type(4)));

__global__ __launch_bounds__(256) void median3_kernel(const float* __restrict__ x,
                                                      float* __restrict__ out,
                                                      int nimg, int cpx) {
    // XCD-aware swizzle (round-5 win)
    int bid = blockIdx.x;
    int swz = (bid % NXCD) * cpx + bid / NXCD;

    int img = swz >> 6;                 // 64 tiles per image (2 x 32)
    if (img >= nimg) return;
    int rem = swz & 63;
    int ty  = rem >> 1;                 // 0..31
    int tx  = rem & 1;                  // 0..1
    int rbase = ty * TR;
    int c0    = tx * TC;

    const float* p = x + (size_t)img * HH * WW;
    int tid = threadIdx.x;

    // LDS tile: rows rbase-1..rbase+16 (18), cols c0-1..c0+256 (258).
    // lds col 3 = image col c0-1 (left halo), 4..259 = main, 260 = right halo.
    __shared__ float lds[18][272];      // row stride 272 floats (16B-aligned)

    // ---- stage main region: 18 rows x 64 float4, fully coalesced ----
#pragma unroll
    for (int it = 0; it < 5; ++it) {
        int idx = it * 256 + tid;
        if (idx < 18 * 64) {
            int row = idx >> 6, c4 = idx & 63;
            int r = rbase + row - 1;
            f32x4 v = {0.f, 0.f, 0.f, 0.f};
            if (r >= 0 && r < HH)
                v = *reinterpret_cast<const f32x4*>(p + (size_t)r * WW + c0 + 4 * c4);
            *reinterpret_cast<f32x4*>(&lds[row][4 + 4 * c4]) = v;
        }
    }
    // ---- stage 36 halo scalars (2 per row) ----
    if (tid < 36) {
        int row = tid >> 1, side = tid & 1;
        int r = rbase + row - 1;
        int ccol = side ? c0 + TC : c0 - 1;
        float v = 0.f;
        if (r >= 0 && r < HH && ccol >= 0 && ccol < WW)
            v = p[(size_t)r * WW + ccol];
        lds[row][side ? 260 : 3] = v;
    }
    __syncthreads();

    // ---- compute: thread = (rg 0..3, cg 0..63) -> 4x4 output patch ----
    int cg = tid & 63;
    int rg = tid >> 6;

    float c[6][6];
#pragma unroll
    for (int dr = 0; dr < 6; ++dr) {
        int lr = 4 * rg + dr;
        f32x4 m = *reinterpret_cast<const f32x4*>(&lds[lr][4 + 4 * cg]);
        c[dr][0] = lds[lr][3 + 4 * cg];
        c[dr][1] = m.x; c[dr][2] = m.y; c[dr][3] = m.z; c[dr][4] = m.w;
        c[dr][5] = lds[lr][8 + 4 * cg];
    }

    float* outp = out + (size_t)img * HH * WW + (size_t)(rbase + 4 * rg) * WW + c0 + 4 * cg;
#pragma unroll
    for (int t = 0; t < 4; ++t) {
        float lo[6], mi[6], hi[6];
#pragma unroll
        for (int j = 0; j < 6; ++j) {
            float a = c[t][j], b = c[t + 1][j], d = c[t + 2][j];
            lo[j] = fminf(fminf(a, b), d);
            hi[j] = fmaxf(fmaxf(a, b), d);
            mi[j] = __builtin_amdgcn_fmed3f(a, b, d);
        }
        f32x4 o;
#pragma unroll
        for (int j = 0; j < 4; ++j) {
            float mx = fmaxf(fmaxf(lo[j], lo[j + 1]), lo[j + 2]);
            float md = __builtin_amdgcn_fmed3f(mi[j], mi[j + 1], mi[j + 2]);
            float mn = fminf(fminf(hi[j], hi[j + 1]), hi[j + 2]);
            o[j] = __builtin_amdgcn_fmed3f(mx, md, mn);
        }
        __builtin_nontemporal_store(o, reinterpret_cast<f32x4*>(outp + (size_t)t * WW));
    }
}

extern "C" void kernel_launch(void* const* d_in, const int* in_sizes, int n_in,
                              void* d_out, int out_size, void* d_ws, size_t ws_size,
                              hipStream_t stream) {
    const float* x = (const float*)d_in[0];
    float* out = (float*)d_out;
    int nimg = in_sizes[0] / (HH * WW);            // 48
    int grid = nimg * (HH / TR) * (WW / TC);       // 48 * 32 * 2 = 3072
    int cpx = grid / NXCD;
    median3_kernel<<<grid, 256, 0, stream>>>(x, out, nimg, cpx);
}

// Round 10
// 20.945 us; speedup vs baseline: 1.0012x; 1.0012x over previous
//
#include <hip/hip_runtime.h>

#define HH 512
#define WW 512
#define XG 128   // col groups  (WW/4)
#define YG 128   // row groups  (HH/4)
#define NXCD 8
#define TILES_PER_BLOCK 2

typedef float f32x4 __attribute__((ext_vector_type(4)));

__global__ __launch_bounds__(256) void median3_kernel(const float* __restrict__ x,
                                                      float* __restrict__ out,
                                                      int nimg, int cpx) {
    // XCD-aware swizzle (round-5 win): contiguous tile chunk per XCD.
    int bid = blockIdx.x;
    int swz = (bid % NXCD) * cpx + bid / NXCD;

#pragma unroll
    for (int k = 0; k < TILES_PER_BLOCK; ++k) {
        int tid = (swz * TILES_PER_BLOCK + k) * blockDim.x + threadIdx.x;

        int xg  = tid & (XG - 1);           // 4-col group
        int yg  = (tid >> 7) & (YG - 1);    // 4-row group
        int img = tid >> 14;
        if (img >= nimg) continue;

        int y0 = yg << 2;
        int c0 = xg << 2;
        const float* p = x + (size_t)img * HH * WW;

        // 6 rows (y0-1 .. y0+4) x 6 cols (c0-1 .. c0+4), zero-padded at borders
        float c[6][6];
#pragma unroll
        for (int dr = 0; dr < 6; ++dr) {
            int r = y0 + dr - 1;
            float4 m = make_float4(0.f, 0.f, 0.f, 0.f);
            float l = 0.f, rr = 0.f;
            if (r >= 0 && r < HH) {          // wave-uniform (yg constant per wave)
                const float* row = p + (size_t)r * WW + c0;
                m = *reinterpret_cast<const float4*>(row);
                if (xg > 0)      l  = row[-1];
                if (xg < XG - 1) rr = row[4];
            }
            c[dr][0] = l;
            c[dr][1] = m.x; c[dr][2] = m.y; c[dr][3] = m.z; c[dr][4] = m.w;
            c[dr][5] = rr;
        }

        float* outp = out + (size_t)img * HH * WW + (size_t)y0 * WW + c0;
#pragma unroll
        for (int t = 0; t < 4; ++t) {
            // sort each of the 6 columns of the 3-row window (t..t+2)
            float lo[6], mi[6], hi[6];
#pragma unroll
            for (int j = 0; j < 6; ++j) {
                float a = c[t][j], b = c[t + 1][j], d = c[t + 2][j];
                lo[j] = fminf(fminf(a, b), d);
                hi[j] = fmaxf(fmaxf(a, b), d);
                mi[j] = __builtin_amdgcn_fmed3f(a, b, d);
            }
            // Smith: median9 = med3(max3(lows), med3(mids), min3(highs))
            f32x4 o;
#pragma unroll
            for (int j = 0; j < 4; ++j) {
                float mx = fmaxf(fmaxf(lo[j], lo[j + 1]), lo[j + 2]);
                float md = __builtin_amdgcn_fmed3f(mi[j], mi[j + 1], mi[j + 2]);
                float mn = fminf(fminf(hi[j], hi[j + 1]), hi[j + 2]);
                o[j] = __builtin_amdgcn_fmed3f(mx, md, mn);
            }
            // Non-temporal (round-8 win): output never re-read; keep L2 for input.
            __builtin_nontemporal_store(o, reinterpret_cast<f32x4*>(outp + (size_t)t * WW));
        }
    }
}

extern "C" void kernel_launch(void* const* d_in, const int* in_sizes, int n_in,
                              void* d_out, int out_size, void* d_ws, size_t ws_size,
                              hipStream_t stream) {
    const float* x = (const float*)d_in[0];
    float* out = (float*)d_out;
    int nimg = in_sizes[0] / (HH * WW);          // 16 * 3 = 48
    int total_threads = nimg * YG * XG;
    int grid = total_threads / (256 * TILES_PER_BLOCK);   // 1536 = 6/CU, all resident
    int cpx = grid / NXCD;                                 // 192
    median3_kernel<<<grid, 256, 0, stream>>>(x, out, nimg, cpx);
}